// Round 3
// baseline (218.377 us; speedup 1.0000x reference)
//
#include <hip/hip_runtime.h>
#include <math.h>

// TSC (order-3) particle-to-mesh deposition.
//
// Fast path (C==8, n even, 36n floats <= 64KB LDS): bucket atoms into 2x2
// column bins via fixed-capacity lists (one atomicAdd kernel, no sort/scan),
// then one block per 2x2 column tile: wave-cooperative deposit (wave = one
// atom, lane = corner, 8 ds_add_f32 per lane) into a channel-interleaved
// pad-9 LDS tile, then single coalesced nontemporal writeout. Bin overflow
// (statistically never) handled by a global-atomic cleanup kernel.
//
// Fallbacks: LDS-atomic scatter tile (C==8), interleaved-atomic two-phase
// (C==8), generic planar atomics.

#define KCAP 64      // atoms per 2x2 bin (mean ~10; Poisson tail ~0)
#define OVFM 4096    // overflow list capacity

// TSC weight for axis offset o in {-1,0,+1} at fractional distance d in [-0.5,0.5]
__device__ __forceinline__ float tsc_w(int o, float d) {
    float t = 0.5f + (float)o * d;
    return (o == 0) ? (0.75f - d * d) : (0.5f * t * t);
}

__device__ __forceinline__ float inv_spacing(const float* __restrict__ cell, int n) {
    float tr = cell[0] + cell[4] + cell[8];
    return (3.0f * (float)n) / tr;
}

// ---------------- binning: fixed-capacity 2x2-column bin lists ----------------

__global__ __launch_bounds__(256) void fill_bins(
    const float* __restrict__ pos, const float* __restrict__ cell,
    int* __restrict__ counts, int* __restrict__ ovf_cnt,
    int* __restrict__ binlist, int* __restrict__ ovf,
    int N, int n, int nby)
{
    int i = blockIdx.x * blockDim.x + threadIdx.x;
    if (i >= N) return;
    float inv_sp = inv_spacing(cell, n);
    float px = pos[3 * i + 0] * inv_sp;
    float py = pos[3 * i + 1] * inv_sp;
    int cx = (int)rintf(px); if (cx >= n) cx -= n; else if (cx < 0) cx += n;
    int cy = (int)rintf(py); if (cy >= n) cy -= n; else if (cy < 0) cy += n;
    int bin = (cx >> 1) * nby + (cy >> 1);
    int slot = atomicAdd(&counts[bin], 1);
    if (slot < KCAP) {
        binlist[bin * KCAP + slot] = i;
    } else {
        int o = atomicAdd(ovf_cnt, 1);
        if (o < OVFM) ovf[o] = i;
    }
}

// ---------------- cooperative tile deposit ----------------
// Block = one 2x2 column tile. LDS tile: [4 cols][n][9] floats (ch 0..7 + pad).
// Wave takes one atom (uniform); lane = corner k<27 (a,b,c); 8 ds_add per lane.

__global__ __launch_bounds__(256) void deposit_coop(
    const float* __restrict__ pos, const float* __restrict__ cell,
    const float* __restrict__ emb, const int* __restrict__ counts,
    const int* __restrict__ binlist, float* __restrict__ out,
    int n, int nbx, int nby)
{
    extern __shared__ float lds[];
    const int tid = threadIdx.x, wid = tid >> 6, lane = tid & 63;
    const int b = blockIdx.x;
    const int bx = b / nby, by = b - bx * nby;
    const int x0 = bx * 2, y0 = by * 2;
    const int nf4 = (36 * n) >> 2;   // 4*n*9 floats / 4

    for (int i = tid; i < nf4; i += 256)
        ((float4*)lds)[i] = make_float4(0.f, 0.f, 0.f, 0.f);

    __shared__ int s_base[9], s_cnt[9];
    if (tid < 9) {
        int dxb = tid / 3 - 1, dyb = tid % 3 - 1;
        int nxb = bx + dxb; if (nxb < 0) nxb += nbx; else if (nxb >= nbx) nxb -= nbx;
        int nyb = by + dyb; if (nyb < 0) nyb += nby; else if (nyb >= nby) nyb -= nby;
        int bb = nxb * nby + nyb;
        s_base[tid] = bb * KCAP;
        int c = counts[bb];
        s_cnt[tid] = (c < KCAP) ? c : KCAP;
    }
    __syncthreads();

    const float inv_sp = inv_spacing(cell, n);
    const int half = n >> 1;

    // per-lane corner decode (constant per lane)
    const int k  = lane;
    const int ka = k / 9;                 // 0..2 (garbage >2 for k>=27, masked)
    const int kr = k - 9 * ka;
    const int kb = kr / 3;
    const int kc = kr - 3 * kb;
    const bool corner_act = (k < 27);
    const float fa = (float)(ka - 1), fb = (float)(kb - 1), fc = (float)(kc - 1);

    for (int j = 0; j < 9; ++j) {
        const int cnt = s_cnt[j];
        const int base = s_base[j];
        for (int t = wid; t < cnt; t += 4) {
            int ai = binlist[base + t];
            float px = pos[3 * ai + 0] * inv_sp;
            float py = pos[3 * ai + 1] * inv_sp;
            float pz = pos[3 * ai + 2] * inv_sp;
            int cx = (int)rintf(px); float dx = px - (float)cx; if (cx >= n) cx -= n;
            int cy = (int)rintf(py); float dy = py - (float)cy; if (cy >= n) cy -= n;
            int cz = (int)rintf(pz); float dz = pz - (float)cz; if (cz >= n) cz -= n;

            int rx = cx - x0; if (rx > half) rx -= n; else if (rx < -half) rx += n;
            if (rx < -1 || rx > 2) continue;          // wave-uniform
            int ry = cy - y0; if (ry > half) ry -= n; else if (ry < -half) ry += n;
            if (ry < -1 || ry > 2) continue;          // wave-uniform

            const float4* e4 = (const float4*)(emb + (size_t)ai * 8);
            float4 e0 = e4[0], e1 = e4[1];            // wave-uniform broadcast

            // lane's corner weight
            float tx = 0.5f + fa * dx;
            float wx = (ka == 1) ? (0.75f - dx * dx) : (0.5f * tx * tx);
            float ty = 0.5f + fb * dy;
            float wy = (kb == 1) ? (0.75f - dy * dy) : (0.5f * ty * ty);
            float tz = 0.5f + fc * dz;
            float wz = (kc == 1) ? (0.75f - dz * dz) : (0.5f * tz * tz);
            float w = wx * wy * wz;

            int lx = rx + ka - 1;
            int ly = ry + kb - 1;
            int lz = cz + kc - 1; if (lz < 0) lz += n; else if (lz >= n) lz -= n;

            if (corner_act && lx >= 0 && lx < 2 && ly >= 0 && ly < 2) {
                float* p = lds + (size_t)(((lx * 2 + ly) * n + lz) * 9);
                atomicAdd(p + 0, w * e0.x);
                atomicAdd(p + 1, w * e0.y);
                atomicAdd(p + 2, w * e0.z);
                atomicAdd(p + 3, w * e0.w);
                atomicAdd(p + 4, w * e1.x);
                atomicAdd(p + 5, w * e1.y);
                atomicAdd(p + 6, w * e1.z);
                atomicAdd(p + 7, w * e1.w);
            }
        }
    }
    __syncthreads();

    // writeout: 32 runs (ch, col) of n contiguous floats; stride-9 LDS reads
    // are conflict-free (gcd(9,32)==1); stores coalesced 256B/wave.
    const int n3 = n * n * n;
    for (int r = wid; r < 32; r += 4) {
        int ch = r >> 2;
        int col = r & 3;
        int lx = col >> 1, ly = col & 1;
        size_t gb = (size_t)ch * n3 + ((size_t)(x0 + lx) * n + (y0 + ly)) * (size_t)n;
        const float* src = lds + (size_t)col * n * 9;
        for (int z = lane; z < n; z += 64)
            __builtin_nontemporal_store(src[z * 9 + ch], out + gb + z);
    }
}

// overflow cleanup: global planar atomics for atoms that missed their bin list
__global__ __launch_bounds__(256) void deposit_overflow(
    const float* __restrict__ pos, const float* __restrict__ cell,
    const float* __restrict__ emb, const int* __restrict__ ovf_cnt,
    const int* __restrict__ ovf, float* __restrict__ out, int n)
{
    int m = *ovf_cnt; if (m > OVFM) m = OVFM;
    int i = blockIdx.x * blockDim.x + threadIdx.x;
    if (i >= m) return;
    int ai = ovf[i];
    float inv_sp = inv_spacing(cell, n);
    float p[3], d[3]; int c0[3];
    #pragma unroll
    for (int kk = 0; kk < 3; ++kk) {
        p[kk] = pos[3 * ai + kk] * inv_sp;
        c0[kk] = (int)rintf(p[kk]);
        d[kk] = p[kk] - (float)c0[kk];
    }
    float w[3][3];
    #pragma unroll
    for (int kk = 0; kk < 3; ++kk) {
        float dd = d[kk];
        w[kk][0] = tsc_w(-1, dd); w[kk][1] = tsc_w(0, dd); w[kk][2] = tsc_w(1, dd);
    }
    int W[3][3];
    #pragma unroll
    for (int kk = 0; kk < 3; ++kk)
        #pragma unroll
        for (int a = 0; a < 3; ++a) {
            int v = c0[kk] - 1 + a; if (v < 0) v += n; else if (v >= n) v -= n;
            W[kk][a] = v;
        }
    size_t n3 = (size_t)n * n * n;
    const float4* e4 = (const float4*)(emb + (size_t)ai * 8);
    float4 e0 = e4[0], e1 = e4[1];
    float e[8] = {e0.x, e0.y, e0.z, e0.w, e1.x, e1.y, e1.z, e1.w};
    for (int a = 0; a < 3; ++a)
        for (int bq = 0; bq < 3; ++bq)
            for (int cq = 0; cq < 3; ++cq) {
                float wt = w[0][a] * w[1][bq] * w[2][cq];
                size_t g = ((size_t)W[0][a] * n + W[1][bq]) * n + W[2][cq];
                #pragma unroll
                for (int ch = 0; ch < 8; ++ch)
                    atomicAdd(out + (size_t)ch * n3 + g, wt * e[ch]);
            }
}

// ---------------- fallback 1: LDS-atomic scatter tile ----------------

#define TX 2
#define TY 2

__global__ __launch_bounds__(256) void hist_bins(
    const float* __restrict__ pos, const float* __restrict__ cell,
    int* __restrict__ counts, int N, int n, int nby)
{
    int i = blockIdx.x * blockDim.x + threadIdx.x;
    if (i >= N) return;
    float inv_sp = inv_spacing(cell, n);
    float px = pos[3 * i + 0] * inv_sp;
    float py = pos[3 * i + 1] * inv_sp;
    int cx = (int)rintf(px); if (cx >= n) cx -= n;
    int cy = (int)rintf(py); if (cy >= n) cy -= n;
    int bin = (cx / TX) * nby + (cy / TY);
    atomicAdd(&counts[bin], 1);
}

__global__ __launch_bounds__(256) void scan_bins(
    const int* __restrict__ counts, int* __restrict__ offsets,
    int* __restrict__ cursors, int nb)
{
    __shared__ int partial[256];
    int tid = threadIdx.x;
    int per = (nb + 255) / 256;
    int lo = tid * per; if (lo > nb) lo = nb;
    int hi = lo + per;  if (hi > nb) hi = nb;
    int s = 0;
    for (int i = lo; i < hi; ++i) s += counts[i];
    partial[tid] = s;
    __syncthreads();
    for (int off = 1; off < 256; off <<= 1) {
        int v = (tid >= off) ? partial[tid - off] : 0;
        __syncthreads();
        partial[tid] += v;
        __syncthreads();
    }
    int run = partial[tid] - s;
    for (int i = lo; i < hi; ++i) {
        offsets[i] = run; cursors[i] = run; run += counts[i];
    }
    if (tid == 255) offsets[nb] = run;
}

__global__ __launch_bounds__(256) void scatter_bins(
    const float* __restrict__ pos, const float* __restrict__ cell,
    int* __restrict__ cursors, int* __restrict__ sidx, int N, int n, int nby)
{
    int i = blockIdx.x * blockDim.x + threadIdx.x;
    if (i >= N) return;
    float inv_sp = inv_spacing(cell, n);
    float px = pos[3 * i + 0] * inv_sp;
    float py = pos[3 * i + 1] * inv_sp;
    int cx = (int)rintf(px); if (cx >= n) cx -= n;
    int cy = (int)rintf(py); if (cy >= n) cy -= n;
    int bin = (cx / TX) * nby + (cy / TY);
    int p = atomicAdd(&cursors[bin], 1);
    sidx[p] = i;
}

__global__ __launch_bounds__(256) void deposit_tiled(
    const float* __restrict__ pos, const float* __restrict__ cell,
    const float* __restrict__ emb, const int* __restrict__ offsets,
    const int* __restrict__ sidx, float* __restrict__ out,
    int n, int nbx, int nby)
{
    extern __shared__ float lds[];
    const int tid = threadIdx.x;
    const int b = blockIdx.x;
    const int bx = b / nby, by = b - bx * nby;
    const int x0 = bx * TX, y0 = by * TY;
    const int plane = TX * TY * n;
    const int sz = 8 * plane;

    for (int i = tid; i < sz; i += 256) lds[i] = 0.0f;

    __shared__ int s_start[9], s_cnt[9];
    if (tid < 9) {
        int dxb = tid / 3 - 1, dyb = tid % 3 - 1;
        int nx = bx + dxb; if (nx < 0) nx += nbx; else if (nx >= nbx) nx -= nbx;
        int ny = by + dyb; if (ny < 0) ny += nby; else if (ny >= nby) ny -= nby;
        int bb = nx * nby + ny;
        int st = offsets[bb];
        s_start[tid] = st;
        s_cnt[tid]   = offsets[bb + 1] - st;
    }
    __syncthreads();

    int pref[10];
    {
        int t = 0;
        #pragma unroll
        for (int j = 0; j < 9; ++j) { pref[j] = t; t += s_cnt[j]; }
        pref[9] = t;
    }
    const int tot = pref[9];
    const float inv_sp = inv_spacing(cell, n);
    const int half = n >> 1;

    for (int w = tid; w < tot; w += 256) {
        int j = 0;
        #pragma unroll
        for (int k = 1; k < 9; ++k) j += (w >= pref[k]);
        int ai = sidx[s_start[j] + (w - pref[j])];

        float px = pos[3 * ai + 0] * inv_sp;
        float py = pos[3 * ai + 1] * inv_sp;
        float pz = pos[3 * ai + 2] * inv_sp;
        int cx = (int)rintf(px); float dx = px - (float)cx;
        int cy = (int)rintf(py); float dy = py - (float)cy;
        int cz = (int)rintf(pz); float dz = pz - (float)cz;
        if (cx >= n) cx -= n;
        if (cy >= n) cy -= n;
        if (cz >= n) cz -= n;

        int rx = cx - x0; if (rx > half) rx -= n; else if (rx < -half) rx += n;
        int ry = cy - y0; if (ry > half) ry -= n; else if (ry < -half) ry += n;
        if (rx < -1 || rx > TX || ry < -1 || ry > TY) continue;

        float wzs[3] = { tsc_w(-1, dz), tsc_w(0, dz), tsc_w(1, dz) };
        int lz0 = cz - 1; if (lz0 < 0) lz0 += n;
        int lz2 = cz + 1; if (lz2 >= n) lz2 -= n;
        int lzs[3] = { lz0, cz, lz2 };

        const float4* e4 = (const float4*)(emb + (size_t)ai * 8);
        float4 e0 = e4[0], e1 = e4[1];

        #pragma unroll
        for (int lx = 0; lx < TX; ++lx) {
            int ox = lx - rx;
            if (ox < -1 || ox > 1) continue;
            float wxv = tsc_w(ox, dx);
            #pragma unroll
            for (int ly = 0; ly < TY; ++ly) {
                int oy = ly - ry;
                if (oy < -1 || oy > 1) continue;
                float wv = wxv * tsc_w(oy, dy);
                int base = (lx * TY + ly) * n;
                #pragma unroll
                for (int q = 0; q < 3; ++q) {
                    float wt = wv * wzs[q];
                    float* p = lds + base + lzs[q];
                    atomicAdd(p + 0 * plane, wt * e0.x);
                    atomicAdd(p + 1 * plane, wt * e0.y);
                    atomicAdd(p + 2 * plane, wt * e0.z);
                    atomicAdd(p + 3 * plane, wt * e0.w);
                    atomicAdd(p + 4 * plane, wt * e1.x);
                    atomicAdd(p + 5 * plane, wt * e1.y);
                    atomicAdd(p + 6 * plane, wt * e1.z);
                    atomicAdd(p + 7 * plane, wt * e1.w);
                }
            }
        }
    }
    __syncthreads();

    const int n3 = n * n * n;
    const int nq = n >> 2;
    const int nf4 = sz >> 2;
    for (int i = tid; i < nf4; i += 256) {
        int r = i / nq; int q = i - r * nq;
        int ch = r >> 2; int lxy = r & 3; int lx = lxy >> 1; int ly = lxy & 1;
        float4 v = *(const float4*)(lds + (size_t)r * n + 4 * q);
        size_t off = (size_t)ch * n3 + ((size_t)(x0 + lx) * n + (y0 + ly)) * n + 4 * q;
        *(float4*)(out + off) = v;
    }
}

// ---------------- fallback 2: interleaved atomics + transpose ----------------

__global__ __launch_bounds__(256) void deposit_tsc8_ilv(
    const float* __restrict__ pos,
    const float* __restrict__ cell,
    const float* __restrict__ emb,
    float* __restrict__ ws,
    int total, int n)
{
    int t = blockIdx.x * blockDim.x + threadIdx.x;
    if (t >= total) return;
    int atom = t / 27;
    int c    = t - atom * 27;
    int a    = c / 9;
    int rem  = c - a * 9;
    int b    = rem / 3;
    int cc   = rem - b * 3;

    float inv_sp = inv_spacing(cell, n);

    float px = pos[3 * atom + 0] * inv_sp;
    float py = pos[3 * atom + 1] * inv_sp;
    float pz = pos[3 * atom + 2] * inv_sp;

    int cx = (int)rintf(px);  float dx = px - (float)cx;
    int cy = (int)rintf(py);  float dy = py - (float)cy;
    int cz = (int)rintf(pz);  float dz = pz - (float)cz;

    float w = tsc_w(a - 1, dx) * tsc_w(b - 1, dy) * tsc_w(cc - 1, dz);

    int x = cx - 1 + a;  if (x < 0) x += n; else if (x >= n) x -= n;
    int y = cy - 1 + b;  if (y < 0) y += n; else if (y >= n) y -= n;
    int z = cz - 1 + cc; if (z < 0) z += n; else if (z >= n) z -= n;

    const float4* e4 = (const float4*)(emb + (size_t)atom * 8);
    float4 e0 = e4[0], e1 = e4[1];

    float* p = ws + ((size_t)((x * n + y) * n + z)) * 8;
    atomicAdd(p + 0, w * e0.x);
    atomicAdd(p + 1, w * e0.y);
    atomicAdd(p + 2, w * e0.z);
    atomicAdd(p + 3, w * e0.w);
    atomicAdd(p + 4, w * e1.x);
    atomicAdd(p + 5, w * e1.y);
    atomicAdd(p + 6, w * e1.z);
    atomicAdd(p + 7, w * e1.w);
}

__global__ __launch_bounds__(256) void transpose_ilv8(
    const float* __restrict__ ws, float* __restrict__ out, int n3)
{
    int t = blockIdx.x * blockDim.x + threadIdx.x;
    int g0 = t * 4;
    if (g0 >= n3) return;
    const float4* w4 = (const float4*)(ws + (size_t)g0 * 8);
    float4 r0 = w4[0], r1 = w4[1];
    float4 r2 = w4[2], r3 = w4[3];
    float4 r4 = w4[4], r5 = w4[5];
    float4 r6 = w4[6], r7 = w4[7];

    *(float4*)(out + (size_t)0 * n3 + g0) = make_float4(r0.x, r2.x, r4.x, r6.x);
    *(float4*)(out + (size_t)1 * n3 + g0) = make_float4(r0.y, r2.y, r4.y, r6.y);
    *(float4*)(out + (size_t)2 * n3 + g0) = make_float4(r0.z, r2.z, r4.z, r6.z);
    *(float4*)(out + (size_t)3 * n3 + g0) = make_float4(r0.w, r2.w, r4.w, r6.w);
    *(float4*)(out + (size_t)4 * n3 + g0) = make_float4(r1.x, r3.x, r5.x, r7.x);
    *(float4*)(out + (size_t)5 * n3 + g0) = make_float4(r1.y, r3.y, r5.y, r7.y);
    *(float4*)(out + (size_t)6 * n3 + g0) = make_float4(r1.z, r3.z, r5.z, r7.z);
    *(float4*)(out + (size_t)7 * n3 + g0) = make_float4(r1.w, r3.w, r5.w, r7.w);
}

// ---------------- fallback 3: generic planar atomics ----------------

__global__ __launch_bounds__(256) void deposit_tsc_gen(
    const float* __restrict__ pos,
    const float* __restrict__ cell,
    const float* __restrict__ emb,
    float* __restrict__ out,
    int N, int n, int C)
{
    int i = blockIdx.x * blockDim.x + threadIdx.x;
    if (i >= N) return;

    float inv_sp = inv_spacing(cell, n);

    float p[3], d[3];
    int c0[3];
    #pragma unroll
    for (int k = 0; k < 3; ++k) {
        p[k] = pos[3 * i + k] * inv_sp;
        c0[k] = (int)rintf(p[k]);
        d[k] = p[k] - (float)c0[k];
    }
    float w[3][3];
    #pragma unroll
    for (int k = 0; k < 3; ++k) {
        float dd = d[k], d2 = dd * dd;
        w[k][0] = 0.125f * (1.0f - 4.0f * dd + 4.0f * d2);
        w[k][1] = 0.25f  * (3.0f - 4.0f * d2);
        w[k][2] = 0.125f * (1.0f + 4.0f * dd + 4.0f * d2);
    }
    int W[3][3];
    #pragma unroll
    for (int k = 0; k < 3; ++k) {
        #pragma unroll
        for (int a = 0; a < 3; ++a) {
            int v = c0[k] - 1 + a; if (v < 0) v += n; else if (v >= n) v -= n;
            W[k][a] = v;
        }
    }
    int n3 = n * n * n;
    for (int a = 0; a < 3; ++a)
        for (int b = 0; b < 3; ++b)
            for (int cc = 0; cc < 3; ++cc) {
                float wt = w[0][a] * w[1][b] * w[2][cc];
                int g = (W[0][a] * n + W[1][b]) * n + W[2][cc];
                for (int ch = 0; ch < C; ++ch)
                    atomicAdd(out + (size_t)ch * n3 + g, wt * emb[(size_t)i * C + ch]);
            }
}

extern "C" void kernel_launch(void* const* d_in, const int* in_sizes, int n_in,
                              void* d_out, int out_size, void* d_ws, size_t ws_size,
                              hipStream_t stream) {
    const float* pos  = (const float*)d_in[0];
    const float* cell = (const float*)d_in[1];
    const float* emb  = (const float*)d_in[2];
    float* out = (float*)d_out;
    float* ws  = (float*)d_ws;

    int N = in_sizes[0] / 3;
    int C = in_sizes[2] / N;
    long long n3l = (long long)out_size / C;
    int n = (int)llroundf(cbrtf((float)n3l));
    int n3 = (int)n3l;

    int block = 256;

    // ---- cooperative tile-scatter fast path ----
    {
        int nbx = n >> 1, nby = n >> 1, nb = nbx * nby;
        size_t lds_bytes = (size_t)36 * n * sizeof(float);   // 4 cols * n * 9
        // ws: counts[nb] | ovf_cnt[1] | pad[3] | ovf[OVFM] | binlist[nb*KCAP]
        size_t need = ((size_t)nb + 4 + OVFM + (size_t)nb * KCAP) * sizeof(int);
        bool coop_ok = (C == 8) && (n % 2 == 0) && nbx >= 3 && nby >= 3
                       && lds_bytes <= 64 * 1024
                       && ws_size >= need
                       && ((long long)n * n * n == n3l);
        if (coop_ok) {
            int* counts  = (int*)d_ws;
            int* ovf_cnt = counts + nb;
            int* ovf     = counts + nb + 4;
            int* binlist = ovf + OVFM;

            hipMemsetAsync(counts, 0, (size_t)(nb + 4) * sizeof(int), stream);
            fill_bins<<<(N + block - 1) / block, block, 0, stream>>>(
                pos, cell, counts, ovf_cnt, binlist, ovf, N, n, nby);
            deposit_coop<<<nb, block, lds_bytes, stream>>>(
                pos, cell, emb, counts, binlist, out, n, nbx, nby);
            deposit_overflow<<<OVFM / block, block, 0, stream>>>(
                pos, cell, emb, ovf_cnt, ovf, out, n);
            return;
        }
    }

    // ---- fallback 1: LDS-atomic scatter tile ----
    {
        int nbx = n / TX, nby = n / TY, nb = nbx * nby;
        size_t lds_bytes  = (size_t)8 * TX * TY * n * sizeof(float);
        size_t ints_need  = (size_t)(nb + (nb + 1) + nb + N) * sizeof(int);
        bool tiled_ok = (C == 8) && (n % 4 == 0) && (n % TX == 0) && (n % TY == 0)
                        && nbx >= 3 && nby >= 3
                        && lds_bytes <= 64 * 1024
                        && ws_size >= ints_need
                        && ((long long)n * n * n == n3l);
        if (tiled_ok) {
            int* counts  = (int*)d_ws;
            int* offsets = counts + nb;
            int* cursors = offsets + nb + 1;
            int* sidx    = cursors + nb;

            hipMemsetAsync(counts, 0, (size_t)nb * sizeof(int), stream);
            hist_bins<<<(N + block - 1) / block, block, 0, stream>>>(
                pos, cell, counts, N, n, nby);
            scan_bins<<<1, block, 0, stream>>>(counts, offsets, cursors, nb);
            scatter_bins<<<(N + block - 1) / block, block, 0, stream>>>(
                pos, cell, cursors, sidx, N, n, nby);
            deposit_tiled<<<nb, block, lds_bytes, stream>>>(
                pos, cell, emb, offsets, sidx, out, n, nbx, nby);
            return;
        }
    }

    // ---- fallback 2/3 ----
    size_t need = (size_t)out_size * sizeof(float);
    if (C == 8 && ws_size >= need && (n3 % 4) == 0) {
        hipMemsetAsync(d_ws, 0, need, stream);
        int total = N * 27;
        deposit_tsc8_ilv<<<(total + block - 1) / block, block, 0, stream>>>(
            pos, cell, emb, ws, total, n);
        int tthreads = n3 / 4;
        transpose_ilv8<<<(tthreads + block - 1) / block, block, 0, stream>>>(
            ws, out, n3);
    } else {
        hipMemsetAsync(d_out, 0, (size_t)out_size * sizeof(float), stream);
        int grid = (N + block - 1) / block;
        deposit_tsc_gen<<<grid, block, 0, stream>>>(pos, cell, emb, out, N, n, C);
    }
}

// Round 4
// 183.741 us; speedup vs baseline: 1.1885x; 1.1885x over previous
//
#include <hip/hip_runtime.h>
#include <math.h>

// TSC (order-3) particle-to-mesh deposition.
//
// Fast path (C==8, n%8==0, 16<=n<=256): per-1x1-column fixed-capacity bin
// lists (one atomicAdd kernel), then x-slab deposit: block = (x, 8 y's, full
// z), LDS tile [8ch][8y][n] = 256n B. Every listed atom in the 3x10 column
// neighborhood is relevant (no filtering); thread-per-visit fire-and-forget
// LDS atomics; writeout is 8 contiguous 32n-byte islands (lds-linear ==
// out-linear per channel) -> long HBM bursts at full write BW. Overflow
// atoms (cap K) handled by a global-atomic cleanup kernel.
//
// Fallbacks: LDS-atomic 2x2 tile (C==8), interleaved-atomic two-phase
// (C==8), generic planar atomics.

#define KColCAP 16   // atoms per 1x1 column bin (lambda ~2.5)
#define TYS 8        // y extent of slab tile

// TSC weight for axis offset o in {-1,0,+1} at fractional distance d in [-0.5,0.5]
__device__ __forceinline__ float tsc_w(int o, float d) {
    float t = 0.5f + (float)o * d;
    return (o == 0) ? (0.75f - d * d) : (0.5f * t * t);
}

__device__ __forceinline__ float inv_spacing(const float* __restrict__ cell, int n) {
    float tr = cell[0] + cell[4] + cell[8];
    return (3.0f * (float)n) / tr;
}

// ---------------- binning: fixed-capacity 1x1-column lists ----------------

__global__ __launch_bounds__(256) void fill_cols(
    const float* __restrict__ pos, const float* __restrict__ cell,
    int* __restrict__ counts, int* __restrict__ ovf_cnt,
    int* __restrict__ binlist, int* __restrict__ ovf,
    int N, int n)
{
    int i = blockIdx.x * blockDim.x + threadIdx.x;
    if (i >= N) return;
    float inv_sp = inv_spacing(cell, n);
    float px = pos[3 * i + 0] * inv_sp;
    float py = pos[3 * i + 1] * inv_sp;
    int cx = (int)rintf(px); if (cx >= n) cx -= n; else if (cx < 0) cx += n;
    int cy = (int)rintf(py); if (cy >= n) cy -= n; else if (cy < 0) cy += n;
    int bin = cx * n + cy;
    int slot = atomicAdd(&counts[bin], 1);
    if (slot < KColCAP) {
        binlist[bin * KColCAP + slot] = i;
    } else {
        int o = atomicAdd(ovf_cnt, 1);
        ovf[o] = i;   // ovf sized N: cannot overflow
    }
}

// ---------------- x-slab deposit ----------------
// Block = (x, y0..y0+7, all z). LDS: [8ch][TYS y][n z] floats (planar).
// Bins needed: (x-1..x+1) x (y0-1..y0+8) = 30 columns; every atom relevant.

__global__ __launch_bounds__(256) void deposit_slab(
    const float* __restrict__ pos, const float* __restrict__ cell,
    const float* __restrict__ emb, const int* __restrict__ counts,
    const int* __restrict__ binlist, float* __restrict__ out,
    int n, int nyg)
{
    extern __shared__ float lds[];
    const int tid = threadIdx.x;
    const int b = blockIdx.x;
    const int x = b / nyg, yg = b - x * nyg;
    const int y0 = yg * TYS;
    const int plane = TYS * n;          // floats per channel
    const int sz4 = (8 * plane) >> 2;   // total float4s

    for (int i = tid; i < sz4; i += 256)
        ((float4*)lds)[i] = make_float4(0.f, 0.f, 0.f, 0.f);

    __shared__ int s_base[30], s_cnt[30];
    if (tid < 30) {
        int dxb = tid / 10 - 1;         // -1,0,1
        int jy  = tid - (tid / 10) * 10;  // 0..9
        int xb = x + dxb; if (xb < 0) xb += n; else if (xb >= n) xb -= n;
        int yb = y0 - 1 + jy; if (yb < 0) yb += n; else if (yb >= n) yb -= n;
        int bin = xb * n + yb;
        s_base[tid] = bin * KColCAP;
        int c = counts[bin];
        s_cnt[tid] = (c < KColCAP) ? c : KColCAP;
    }
    __syncthreads();

    // per-thread register prefix over the 30 bins (broadcast LDS reads)
    int pref[31];
    pref[0] = 0;
    #pragma unroll
    for (int j = 0; j < 30; ++j) pref[j + 1] = pref[j] + s_cnt[j];
    const int tot = pref[30];

    const float inv_sp = inv_spacing(cell, n);
    const int half = n >> 1;

    for (int v = tid; v < tot; v += 256) {
        int j = 0;
        #pragma unroll
        for (int k = 1; k < 30; ++k) j += (v >= pref[k]);
        int ai = binlist[s_base[j] + (v - pref[j])];

        float px = pos[3 * ai + 0] * inv_sp;
        float py = pos[3 * ai + 1] * inv_sp;
        float pz = pos[3 * ai + 2] * inv_sp;
        int cx = (int)rintf(px); float dx = px - (float)cx;
        int cy = (int)rintf(py); float dy = py - (float)cy;
        int cz = (int)rintf(pz); float dz = pz - (float)cz;
        if (cx >= n) cx -= n; else if (cx < 0) cx += n;
        if (cy >= n) cy -= n; else if (cy < 0) cy += n;
        if (cz >= n) cz -= n; else if (cz < 0) cz += n;

        // guaranteed: rx in {-1,0,1}, ry in [-1,TYS]
        int rx = cx - x;  if (rx > half) rx -= n; else if (rx < -half) rx += n;
        int ry = cy - y0; if (ry > half) ry -= n; else if (ry < -half) ry += n;

        float wx = tsc_w(-rx, dx);   // single in-tile x corner (lx == 0)

        float wy0 = tsc_w(-1, dy), wy1 = tsc_w(0, dy), wy2 = tsc_w(1, dy);
        float wz0 = tsc_w(-1, dz), wz1 = tsc_w(0, dz), wz2 = tsc_w(1, dz);
        float wys[3] = { wx * wy0, wx * wy1, wx * wy2 };
        float wzs[3] = { wz0, wz1, wz2 };
        int lz0 = cz - 1; if (lz0 < 0) lz0 += n;
        int lz2 = cz + 1; if (lz2 >= n) lz2 -= n;
        int lzs[3] = { lz0, cz, lz2 };

        const float4* e4 = (const float4*)(emb + (size_t)ai * 8);
        float4 e0 = e4[0], e1 = e4[1];

        #pragma unroll
        for (int kb = 0; kb < 3; ++kb) {
            int ly = ry + kb - 1;
            if (ly < 0 || ly >= TYS) continue;
            float wvy = wys[kb];
            #pragma unroll
            for (int kc = 0; kc < 3; ++kc) {
                float w = wvy * wzs[kc];
                float* p = lds + ly * n + lzs[kc];
                atomicAdd(p + 0 * plane, w * e0.x);
                atomicAdd(p + 1 * plane, w * e0.y);
                atomicAdd(p + 2 * plane, w * e0.z);
                atomicAdd(p + 3 * plane, w * e0.w);
                atomicAdd(p + 4 * plane, w * e1.x);
                atomicAdd(p + 5 * plane, w * e1.y);
                atomicAdd(p + 6 * plane, w * e1.z);
                atomicAdd(p + 7 * plane, w * e1.w);
            }
        }
    }
    __syncthreads();

    // writeout: per channel, lds [ch][0..TYS*n) maps linearly to
    // out[ch][x][y0*n .. y0*n + TYS*n) -> 8 contiguous 4*TYS*n-byte islands.
    const size_t n3 = (size_t)n * n * n;
    const int chunk = plane >> 2;   // float4s per channel
    #pragma unroll
    for (int ch = 0; ch < 8; ++ch) {
        const float4* src = (const float4*)(lds + (size_t)ch * plane);
        float4* dst = (float4*)(out + (size_t)ch * n3 + (size_t)x * n * n + (size_t)y0 * n);
        for (int i = tid; i < chunk; i += 256)
            dst[i] = src[i];
    }
}

// overflow cleanup: global planar atomics for atoms that missed their bin list
__global__ __launch_bounds__(256) void deposit_overflow(
    const float* __restrict__ pos, const float* __restrict__ cell,
    const float* __restrict__ emb, const int* __restrict__ ovf_cnt,
    const int* __restrict__ ovf, float* __restrict__ out, int n)
{
    int m = *ovf_cnt;
    int i = blockIdx.x * blockDim.x + threadIdx.x;
    if (i >= m) return;
    int ai = ovf[i];
    float inv_sp = inv_spacing(cell, n);
    float p[3], d[3]; int c0[3];
    #pragma unroll
    for (int kk = 0; kk < 3; ++kk) {
        p[kk] = pos[3 * ai + kk] * inv_sp;
        c0[kk] = (int)rintf(p[kk]);
        d[kk] = p[kk] - (float)c0[kk];
    }
    float w[3][3];
    #pragma unroll
    for (int kk = 0; kk < 3; ++kk) {
        float dd = d[kk];
        w[kk][0] = tsc_w(-1, dd); w[kk][1] = tsc_w(0, dd); w[kk][2] = tsc_w(1, dd);
    }
    int W[3][3];
    #pragma unroll
    for (int kk = 0; kk < 3; ++kk)
        #pragma unroll
        for (int a = 0; a < 3; ++a) {
            int v = c0[kk] - 1 + a; if (v < 0) v += n; else if (v >= n) v -= n;
            W[kk][a] = v;
        }
    size_t n3 = (size_t)n * n * n;
    const float4* e4 = (const float4*)(emb + (size_t)ai * 8);
    float4 e0 = e4[0], e1 = e4[1];
    float e[8] = {e0.x, e0.y, e0.z, e0.w, e1.x, e1.y, e1.z, e1.w};
    for (int a = 0; a < 3; ++a)
        for (int bq = 0; bq < 3; ++bq)
            for (int cq = 0; cq < 3; ++cq) {
                float wt = w[0][a] * w[1][bq] * w[2][cq];
                size_t g = ((size_t)W[0][a] * n + W[1][bq]) * n + W[2][cq];
                #pragma unroll
                for (int ch = 0; ch < 8; ++ch)
                    atomicAdd(out + (size_t)ch * n3 + g, wt * e[ch]);
            }
}

// ---------------- fallback 1: LDS-atomic 2x2 scatter tile ----------------

#define TX 2
#define TY 2

__global__ __launch_bounds__(256) void hist_bins(
    const float* __restrict__ pos, const float* __restrict__ cell,
    int* __restrict__ counts, int N, int n, int nby)
{
    int i = blockIdx.x * blockDim.x + threadIdx.x;
    if (i >= N) return;
    float inv_sp = inv_spacing(cell, n);
    float px = pos[3 * i + 0] * inv_sp;
    float py = pos[3 * i + 1] * inv_sp;
    int cx = (int)rintf(px); if (cx >= n) cx -= n;
    int cy = (int)rintf(py); if (cy >= n) cy -= n;
    int bin = (cx / TX) * nby + (cy / TY);
    atomicAdd(&counts[bin], 1);
}

__global__ __launch_bounds__(256) void scan_bins(
    const int* __restrict__ counts, int* __restrict__ offsets,
    int* __restrict__ cursors, int nb)
{
    __shared__ int partial[256];
    int tid = threadIdx.x;
    int per = (nb + 255) / 256;
    int lo = tid * per; if (lo > nb) lo = nb;
    int hi = lo + per;  if (hi > nb) hi = nb;
    int s = 0;
    for (int i = lo; i < hi; ++i) s += counts[i];
    partial[tid] = s;
    __syncthreads();
    for (int off = 1; off < 256; off <<= 1) {
        int v = (tid >= off) ? partial[tid - off] : 0;
        __syncthreads();
        partial[tid] += v;
        __syncthreads();
    }
    int run = partial[tid] - s;
    for (int i = lo; i < hi; ++i) {
        offsets[i] = run; cursors[i] = run; run += counts[i];
    }
    if (tid == 255) offsets[nb] = run;
}

__global__ __launch_bounds__(256) void scatter_bins(
    const float* __restrict__ pos, const float* __restrict__ cell,
    int* __restrict__ cursors, int* __restrict__ sidx, int N, int n, int nby)
{
    int i = blockIdx.x * blockDim.x + threadIdx.x;
    if (i >= N) return;
    float inv_sp = inv_spacing(cell, n);
    float px = pos[3 * i + 0] * inv_sp;
    float py = pos[3 * i + 1] * inv_sp;
    int cx = (int)rintf(px); if (cx >= n) cx -= n;
    int cy = (int)rintf(py); if (cy >= n) cy -= n;
    int bin = (cx / TX) * nby + (cy / TY);
    int p = atomicAdd(&cursors[bin], 1);
    sidx[p] = i;
}

__global__ __launch_bounds__(256) void deposit_tiled(
    const float* __restrict__ pos, const float* __restrict__ cell,
    const float* __restrict__ emb, const int* __restrict__ offsets,
    const int* __restrict__ sidx, float* __restrict__ out,
    int n, int nbx, int nby)
{
    extern __shared__ float lds[];
    const int tid = threadIdx.x;
    const int b = blockIdx.x;
    const int bx = b / nby, by = b - bx * nby;
    const int x0 = bx * TX, y0 = by * TY;
    const int plane = TX * TY * n;
    const int sz = 8 * plane;

    for (int i = tid; i < sz; i += 256) lds[i] = 0.0f;

    __shared__ int s_start[9], s_cnt[9];
    if (tid < 9) {
        int dxb = tid / 3 - 1, dyb = tid % 3 - 1;
        int nx = bx + dxb; if (nx < 0) nx += nbx; else if (nx >= nbx) nx -= nbx;
        int ny = by + dyb; if (ny < 0) ny += nby; else if (ny >= nby) ny -= nby;
        int bb = nx * nby + ny;
        int st = offsets[bb];
        s_start[tid] = st;
        s_cnt[tid]   = offsets[bb + 1] - st;
    }
    __syncthreads();

    int pref[10];
    {
        int t = 0;
        #pragma unroll
        for (int j = 0; j < 9; ++j) { pref[j] = t; t += s_cnt[j]; }
        pref[9] = t;
    }
    const int tot = pref[9];
    const float inv_sp = inv_spacing(cell, n);
    const int half = n >> 1;

    for (int w = tid; w < tot; w += 256) {
        int j = 0;
        #pragma unroll
        for (int k = 1; k < 9; ++k) j += (w >= pref[k]);
        int ai = sidx[s_start[j] + (w - pref[j])];

        float px = pos[3 * ai + 0] * inv_sp;
        float py = pos[3 * ai + 1] * inv_sp;
        float pz = pos[3 * ai + 2] * inv_sp;
        int cx = (int)rintf(px); float dx = px - (float)cx;
        int cy = (int)rintf(py); float dy = py - (float)cy;
        int cz = (int)rintf(pz); float dz = pz - (float)cz;
        if (cx >= n) cx -= n;
        if (cy >= n) cy -= n;
        if (cz >= n) cz -= n;

        int rx = cx - x0; if (rx > half) rx -= n; else if (rx < -half) rx += n;
        int ry = cy - y0; if (ry > half) ry -= n; else if (ry < -half) ry += n;
        if (rx < -1 || rx > TX || ry < -1 || ry > TY) continue;

        float wzs[3] = { tsc_w(-1, dz), tsc_w(0, dz), tsc_w(1, dz) };
        int lz0 = cz - 1; if (lz0 < 0) lz0 += n;
        int lz2 = cz + 1; if (lz2 >= n) lz2 -= n;
        int lzs[3] = { lz0, cz, lz2 };

        const float4* e4 = (const float4*)(emb + (size_t)ai * 8);
        float4 e0 = e4[0], e1 = e4[1];

        #pragma unroll
        for (int lx = 0; lx < TX; ++lx) {
            int ox = lx - rx;
            if (ox < -1 || ox > 1) continue;
            float wxv = tsc_w(ox, dx);
            #pragma unroll
            for (int ly = 0; ly < TY; ++ly) {
                int oy = ly - ry;
                if (oy < -1 || oy > 1) continue;
                float wv = wxv * tsc_w(oy, dy);
                int base = (lx * TY + ly) * n;
                #pragma unroll
                for (int q = 0; q < 3; ++q) {
                    float wt = wv * wzs[q];
                    float* p = lds + base + lzs[q];
                    atomicAdd(p + 0 * plane, wt * e0.x);
                    atomicAdd(p + 1 * plane, wt * e0.y);
                    atomicAdd(p + 2 * plane, wt * e0.z);
                    atomicAdd(p + 3 * plane, wt * e0.w);
                    atomicAdd(p + 4 * plane, wt * e1.x);
                    atomicAdd(p + 5 * plane, wt * e1.y);
                    atomicAdd(p + 6 * plane, wt * e1.z);
                    atomicAdd(p + 7 * plane, wt * e1.w);
                }
            }
        }
    }
    __syncthreads();

    const int n3 = n * n * n;
    const int nq = n >> 2;
    const int nf4 = sz >> 2;
    for (int i = tid; i < nf4; i += 256) {
        int r = i / nq; int q = i - r * nq;
        int ch = r >> 2; int lxy = r & 3; int lx = lxy >> 1; int ly = lxy & 1;
        float4 v = *(const float4*)(lds + (size_t)r * n + 4 * q);
        size_t off = (size_t)ch * n3 + ((size_t)(x0 + lx) * n + (y0 + ly)) * n + 4 * q;
        *(float4*)(out + off) = v;
    }
}

// ---------------- fallback 2: interleaved atomics + transpose ----------------

__global__ __launch_bounds__(256) void deposit_tsc8_ilv(
    const float* __restrict__ pos,
    const float* __restrict__ cell,
    const float* __restrict__ emb,
    float* __restrict__ ws,
    int total, int n)
{
    int t = blockIdx.x * blockDim.x + threadIdx.x;
    if (t >= total) return;
    int atom = t / 27;
    int c    = t - atom * 27;
    int a    = c / 9;
    int rem  = c - a * 9;
    int b    = rem / 3;
    int cc   = rem - b * 3;

    float inv_sp = inv_spacing(cell, n);

    float px = pos[3 * atom + 0] * inv_sp;
    float py = pos[3 * atom + 1] * inv_sp;
    float pz = pos[3 * atom + 2] * inv_sp;

    int cx = (int)rintf(px);  float dx = px - (float)cx;
    int cy = (int)rintf(py);  float dy = py - (float)cy;
    int cz = (int)rintf(pz);  float dz = pz - (float)cz;

    float w = tsc_w(a - 1, dx) * tsc_w(b - 1, dy) * tsc_w(cc - 1, dz);

    int x = cx - 1 + a;  if (x < 0) x += n; else if (x >= n) x -= n;
    int y = cy - 1 + b;  if (y < 0) y += n; else if (y >= n) y -= n;
    int z = cz - 1 + cc; if (z < 0) z += n; else if (z >= n) z -= n;

    const float4* e4 = (const float4*)(emb + (size_t)atom * 8);
    float4 e0 = e4[0], e1 = e4[1];

    float* p = ws + ((size_t)((x * n + y) * n + z)) * 8;
    atomicAdd(p + 0, w * e0.x);
    atomicAdd(p + 1, w * e0.y);
    atomicAdd(p + 2, w * e0.z);
    atomicAdd(p + 3, w * e0.w);
    atomicAdd(p + 4, w * e1.x);
    atomicAdd(p + 5, w * e1.y);
    atomicAdd(p + 6, w * e1.z);
    atomicAdd(p + 7, w * e1.w);
}

__global__ __launch_bounds__(256) void transpose_ilv8(
    const float* __restrict__ ws, float* __restrict__ out, int n3)
{
    int t = blockIdx.x * blockDim.x + threadIdx.x;
    int g0 = t * 4;
    if (g0 >= n3) return;
    const float4* w4 = (const float4*)(ws + (size_t)g0 * 8);
    float4 r0 = w4[0], r1 = w4[1];
    float4 r2 = w4[2], r3 = w4[3];
    float4 r4 = w4[4], r5 = w4[5];
    float4 r6 = w4[6], r7 = w4[7];

    *(float4*)(out + (size_t)0 * n3 + g0) = make_float4(r0.x, r2.x, r4.x, r6.x);
    *(float4*)(out + (size_t)1 * n3 + g0) = make_float4(r0.y, r2.y, r4.y, r6.y);
    *(float4*)(out + (size_t)2 * n3 + g0) = make_float4(r0.z, r2.z, r4.z, r6.z);
    *(float4*)(out + (size_t)3 * n3 + g0) = make_float4(r0.w, r2.w, r4.w, r6.w);
    *(float4*)(out + (size_t)4 * n3 + g0) = make_float4(r1.x, r3.x, r5.x, r7.x);
    *(float4*)(out + (size_t)5 * n3 + g0) = make_float4(r1.y, r3.y, r5.y, r7.y);
    *(float4*)(out + (size_t)6 * n3 + g0) = make_float4(r1.z, r3.z, r5.z, r7.z);
    *(float4*)(out + (size_t)7 * n3 + g0) = make_float4(r1.w, r3.w, r5.w, r7.w);
}

// ---------------- fallback 3: generic planar atomics ----------------

__global__ __launch_bounds__(256) void deposit_tsc_gen(
    const float* __restrict__ pos,
    const float* __restrict__ cell,
    const float* __restrict__ emb,
    float* __restrict__ out,
    int N, int n, int C)
{
    int i = blockIdx.x * blockDim.x + threadIdx.x;
    if (i >= N) return;

    float inv_sp = inv_spacing(cell, n);

    float p[3], d[3];
    int c0[3];
    #pragma unroll
    for (int k = 0; k < 3; ++k) {
        p[k] = pos[3 * i + k] * inv_sp;
        c0[k] = (int)rintf(p[k]);
        d[k] = p[k] - (float)c0[k];
    }
    float w[3][3];
    #pragma unroll
    for (int k = 0; k < 3; ++k) {
        float dd = d[k], d2 = dd * dd;
        w[k][0] = 0.125f * (1.0f - 4.0f * dd + 4.0f * d2);
        w[k][1] = 0.25f  * (3.0f - 4.0f * d2);
        w[k][2] = 0.125f * (1.0f + 4.0f * dd + 4.0f * d2);
    }
    int W[3][3];
    #pragma unroll
    for (int k = 0; k < 3; ++k) {
        #pragma unroll
        for (int a = 0; a < 3; ++a) {
            int v = c0[k] - 1 + a; if (v < 0) v += n; else if (v >= n) v -= n;
            W[k][a] = v;
        }
    }
    int n3 = n * n * n;
    for (int a = 0; a < 3; ++a)
        for (int b = 0; b < 3; ++b)
            for (int cc = 0; cc < 3; ++cc) {
                float wt = w[0][a] * w[1][b] * w[2][cc];
                int g = (W[0][a] * n + W[1][b]) * n + W[2][cc];
                for (int ch = 0; ch < C; ++ch)
                    atomicAdd(out + (size_t)ch * n3 + g, wt * emb[(size_t)i * C + ch]);
            }
}

extern "C" void kernel_launch(void* const* d_in, const int* in_sizes, int n_in,
                              void* d_out, int out_size, void* d_ws, size_t ws_size,
                              hipStream_t stream) {
    const float* pos  = (const float*)d_in[0];
    const float* cell = (const float*)d_in[1];
    const float* emb  = (const float*)d_in[2];
    float* out = (float*)d_out;
    float* ws  = (float*)d_ws;

    int N = in_sizes[0] / 3;
    int C = in_sizes[2] / N;
    long long n3l = (long long)out_size / C;
    int n = (int)llroundf(cbrtf((float)n3l));
    int n3 = (int)n3l;

    int block = 256;

    // ---- x-slab fast path ----
    {
        int nb = n * n;
        size_t lds_bytes = (size_t)8 * TYS * n * sizeof(float);   // 256n B
        // ws: counts[nb] | ovf_cnt(+pad)[4] | ovf[N] | binlist[nb*KColCAP]
        size_t need = ((size_t)nb + 4 + (size_t)N + (size_t)nb * KColCAP) * sizeof(int);
        bool slab_ok = (C == 8) && (n % TYS == 0) && n >= 16 && n <= 256
                       && lds_bytes <= 64 * 1024
                       && ws_size >= need
                       && ((long long)n * n * n == n3l);
        if (slab_ok) {
            int* counts  = (int*)d_ws;
            int* ovf_cnt = counts + nb;
            int* ovf     = counts + nb + 4;
            int* binlist = ovf + N;

            hipMemsetAsync(counts, 0, (size_t)(nb + 4) * sizeof(int), stream);
            fill_cols<<<(N + block - 1) / block, block, 0, stream>>>(
                pos, cell, counts, ovf_cnt, binlist, ovf, N, n);
            int nyg = n / TYS;
            deposit_slab<<<n * nyg, block, lds_bytes, stream>>>(
                pos, cell, emb, counts, binlist, out, n, nyg);
            deposit_overflow<<<(N + block - 1) / block, block, 0, stream>>>(
                pos, cell, emb, ovf_cnt, ovf, out, n);
            return;
        }
    }

    // ---- fallback 1: LDS-atomic 2x2 scatter tile ----
    {
        int nbx = n / TX, nby = n / TY, nb = nbx * nby;
        size_t lds_bytes  = (size_t)8 * TX * TY * n * sizeof(float);
        size_t ints_need  = (size_t)(nb + (nb + 1) + nb + N) * sizeof(int);
        bool tiled_ok = (C == 8) && (n % 4 == 0) && (n % TX == 0) && (n % TY == 0)
                        && nbx >= 3 && nby >= 3
                        && lds_bytes <= 64 * 1024
                        && ws_size >= ints_need
                        && ((long long)n * n * n == n3l);
        if (tiled_ok) {
            int* counts  = (int*)d_ws;
            int* offsets = counts + nb;
            int* cursors = offsets + nb + 1;
            int* sidx    = cursors + nb;

            hipMemsetAsync(counts, 0, (size_t)nb * sizeof(int), stream);
            hist_bins<<<(N + block - 1) / block, block, 0, stream>>>(
                pos, cell, counts, N, n, nby);
            scan_bins<<<1, block, 0, stream>>>(counts, offsets, cursors, nb);
            scatter_bins<<<(N + block - 1) / block, block, 0, stream>>>(
                pos, cell, cursors, sidx, N, n, nby);
            deposit_tiled<<<nb, block, lds_bytes, stream>>>(
                pos, cell, emb, offsets, sidx, out, n, nbx, nby);
            return;
        }
    }

    // ---- fallback 2/3 ----
    size_t need = (size_t)out_size * sizeof(float);
    if (C == 8 && ws_size >= need && (n3 % 4) == 0) {
        hipMemsetAsync(d_ws, 0, need, stream);
        int total = N * 27;
        deposit_tsc8_ilv<<<(total + block - 1) / block, block, 0, stream>>>(
            pos, cell, emb, ws, total, n);
        int tthreads = n3 / 4;
        transpose_ilv8<<<(tthreads + block - 1) / block, block, 0, stream>>>(
            ws, out, n3);
    } else {
        hipMemsetAsync(d_out, 0, (size_t)out_size * sizeof(float), stream);
        int grid = (N + block - 1) / block;
        deposit_tsc_gen<<<grid, block, 0, stream>>>(pos, cell, emb, out, N, n, C);
    }
}

// Round 6
// 157.902 us; speedup vs baseline: 1.3830x; 1.1636x over previous
//
#include <hip/hip_runtime.h>
#include <math.h>

// TSC (order-3) particle-to-mesh deposition.
//
// Fast path (C==8, n even): per-1x1-column fixed-capacity bin lists holding
// PACKED 48B records (pos.xyz + 8 emb), then x-slab deposit with a SMALL
// tile: block = (x, 2 y's, full z), LDS [8ch][2][n] = 64n B (12.8 KB at
// n=200) -> ~12 blocks/CU resident: many staggered store streams per CU
// keep the HBM write pipe at high duty cycle (the r1/r3/r4 designs stalled
// at ~1.7 TB/s with 2-3 blocks/CU). Every listed atom is relevant (bins are
// exact columns); single x-corner per atom; LDS fire-and-forget atomics;
// per-channel contiguous nontemporal writeout. Overflow atoms handled by a
// global-atomic cleanup kernel.
//
// Fallbacks: interleaved-atomic two-phase (C==8), generic planar atomics.

#define KColCAP 16   // records per 1x1 column bin (lambda ~2.5)
#define TYS 2        // y extent of slab tile
#define BLK 128      // threads per block (2 waves)

// native 16B vector type usable with __builtin_nontemporal_store
typedef float nfloat4 __attribute__((ext_vector_type(4)));

// TSC weight for axis offset o in {-1,0,+1} at fractional distance d in [-0.5,0.5]
__device__ __forceinline__ float tsc_w(int o, float d) {
    float t = 0.5f + (float)o * d;
    return (o == 0) ? (0.75f - d * d) : (0.5f * t * t);
}

__device__ __forceinline__ float inv_spacing(const float* __restrict__ cell, int n) {
    float tr = cell[0] + cell[4] + cell[8];
    return (3.0f * (float)n) / tr;
}

// ---------------- binning: packed records into 1x1-column lists ----------------

__global__ __launch_bounds__(256) void fill_recs(
    const float* __restrict__ pos, const float* __restrict__ cell,
    const float* __restrict__ emb,
    int* __restrict__ counts, int* __restrict__ ovf_cnt,
    float4* __restrict__ binrec, int* __restrict__ ovf,
    int N, int n)
{
    int i = blockIdx.x * blockDim.x + threadIdx.x;
    if (i >= N) return;
    float inv_sp = inv_spacing(cell, n);
    float px = pos[3 * i + 0] * inv_sp;
    float py = pos[3 * i + 1] * inv_sp;
    float pz = pos[3 * i + 2] * inv_sp;
    int cx = (int)rintf(px); if (cx >= n) cx -= n; else if (cx < 0) cx += n;
    int cy = (int)rintf(py); if (cy >= n) cy -= n; else if (cy < 0) cy += n;
    int bin = cx * n + cy;
    int slot = atomicAdd(&counts[bin], 1);
    if (slot < KColCAP) {
        const float4* e4 = (const float4*)(emb + (size_t)i * 8);
        float4* r = binrec + (size_t)(bin * KColCAP + slot) * 3;
        r[0] = make_float4(px, py, pz, 0.0f);
        r[1] = e4[0];
        r[2] = e4[1];
    } else {
        int o = atomicAdd(ovf_cnt, 1);
        ovf[o] = i;   // ovf sized N: cannot overflow
    }
}

// ---------------- x-slab deposit, small tile ----------------
// Block = (x, y0..y0+1, all z). LDS: [8ch][TYS][n] floats.
// Bins: (x-1..x+1) x (y0-1..y0+2) = 12 columns; every atom relevant.

__global__ __launch_bounds__(BLK) void deposit_slab2(
    const float4* __restrict__ binrec, const int* __restrict__ counts,
    float* __restrict__ out, int n, int nyg)
{
    extern __shared__ float lds[];
    const int tid = threadIdx.x;
    const int b = blockIdx.x;
    const int x = b / nyg, yg = b - x * nyg;
    const int y0 = yg * TYS;
    const int plane = TYS * n;          // floats per channel
    const int sz4 = (8 * plane) >> 2;   // total float4s (= 4n)

    for (int i = tid; i < sz4; i += BLK)
        ((float4*)lds)[i] = make_float4(0.f, 0.f, 0.f, 0.f);

    __shared__ int s_base[12], s_cnt[12], s_pref[13];
    if (tid < 12) {
        int dxb = tid / 4 - 1;            // -1,0,1
        int jy  = tid & 3;                // 0..3
        int xb = x + dxb; if (xb < 0) xb += n; else if (xb >= n) xb -= n;
        int yb = y0 - 1 + jy; if (yb < 0) yb += n; else if (yb >= n) yb -= n;
        int bin = xb * n + yb;
        s_base[tid] = bin * KColCAP;
        int c = counts[bin];
        s_cnt[tid] = (c < KColCAP) ? c : KColCAP;
    }
    __syncthreads();
    if (tid == 0) {
        int r = 0;
        #pragma unroll
        for (int j = 0; j < 12; ++j) { s_pref[j] = r; r += s_cnt[j]; }
        s_pref[12] = r;
    }
    __syncthreads();
    const int tot = s_pref[12];
    const int half = n >> 1;

    for (int v = tid; v < tot; v += BLK) {
        int j = 0;
        #pragma unroll
        for (int k = 1; k < 12; ++k) j += (v >= s_pref[k]);
        const float4* rp = binrec + (size_t)(s_base[j] + (v - s_pref[j])) * 3;
        float4 P  = rp[0];
        float4 e0 = rp[1];
        float4 e1 = rp[2];

        int cx = (int)rintf(P.x); float dx = P.x - (float)cx;
        int cy = (int)rintf(P.y); float dy = P.y - (float)cy;
        int cz = (int)rintf(P.z); float dz = P.z - (float)cz;
        if (cx >= n) cx -= n; else if (cx < 0) cx += n;
        if (cy >= n) cy -= n; else if (cy < 0) cy += n;
        if (cz >= n) cz -= n; else if (cz < 0) cz += n;

        int rx = cx - x;  if (rx > half) rx -= n; else if (rx < -half) rx += n;
        int ry = cy - y0; if (ry > half) ry -= n; else if (ry < -half) ry += n;

        float wx = tsc_w(-rx, dx);   // single in-tile x corner

        float wys[3] = { wx * tsc_w(-1, dy), wx * tsc_w(0, dy), wx * tsc_w(1, dy) };
        float wzs[3] = { tsc_w(-1, dz), tsc_w(0, dz), tsc_w(1, dz) };
        int lz0 = cz - 1; if (lz0 < 0) lz0 += n;
        int lz2 = cz + 1; if (lz2 >= n) lz2 -= n;
        int lzs[3] = { lz0, cz, lz2 };

        #pragma unroll
        for (int kb = 0; kb < 3; ++kb) {
            int ly = ry + kb - 1;
            if (ly < 0 || ly >= TYS) continue;
            float wvy = wys[kb];
            #pragma unroll
            for (int kc = 0; kc < 3; ++kc) {
                float w = wvy * wzs[kc];
                float* p = lds + ly * n + lzs[kc];
                atomicAdd(p + 0 * plane, w * e0.x);
                atomicAdd(p + 1 * plane, w * e0.y);
                atomicAdd(p + 2 * plane, w * e0.z);
                atomicAdd(p + 3 * plane, w * e0.w);
                atomicAdd(p + 4 * plane, w * e1.x);
                atomicAdd(p + 5 * plane, w * e1.y);
                atomicAdd(p + 6 * plane, w * e1.z);
                atomicAdd(p + 7 * plane, w * e1.w);
            }
        }
    }
    __syncthreads();

    // writeout: per channel, lds[ch][0..TYS*n) -> out[ch][x][y0*n ..] linear,
    // contiguous 4*TYS*n bytes per channel. Nontemporal (never re-read).
    const size_t n3 = (size_t)n * n * n;
    const int chunk = plane >> 2;   // float4s per channel
    #pragma unroll
    for (int ch = 0; ch < 8; ++ch) {
        const nfloat4* src = (const nfloat4*)(lds + (size_t)ch * plane);
        nfloat4* dst = (nfloat4*)(out + (size_t)ch * n3 + (size_t)x * n * n + (size_t)y0 * n);
        for (int i = tid; i < chunk; i += BLK)
            __builtin_nontemporal_store(src[i], dst + i);
    }
}

// overflow cleanup: global planar atomics for atoms that missed their bin list
__global__ __launch_bounds__(256) void deposit_overflow(
    const float* __restrict__ pos, const float* __restrict__ cell,
    const float* __restrict__ emb, const int* __restrict__ ovf_cnt,
    const int* __restrict__ ovf, float* __restrict__ out, int n)
{
    int m = *ovf_cnt;
    int i = blockIdx.x * blockDim.x + threadIdx.x;
    if (i >= m) return;
    int ai = ovf[i];
    float inv_sp = inv_spacing(cell, n);
    float p[3], d[3]; int c0[3];
    #pragma unroll
    for (int kk = 0; kk < 3; ++kk) {
        p[kk] = pos[3 * ai + kk] * inv_sp;
        c0[kk] = (int)rintf(p[kk]);
        d[kk] = p[kk] - (float)c0[kk];
    }
    float w[3][3];
    #pragma unroll
    for (int kk = 0; kk < 3; ++kk) {
        float dd = d[kk];
        w[kk][0] = tsc_w(-1, dd); w[kk][1] = tsc_w(0, dd); w[kk][2] = tsc_w(1, dd);
    }
    int W[3][3];
    #pragma unroll
    for (int kk = 0; kk < 3; ++kk)
        #pragma unroll
        for (int a = 0; a < 3; ++a) {
            int v = c0[kk] - 1 + a; if (v < 0) v += n; else if (v >= n) v -= n;
            W[kk][a] = v;
        }
    size_t n3 = (size_t)n * n * n;
    const float4* e4 = (const float4*)(emb + (size_t)ai * 8);
    float4 e0 = e4[0], e1 = e4[1];
    float e[8] = {e0.x, e0.y, e0.z, e0.w, e1.x, e1.y, e1.z, e1.w};
    for (int a = 0; a < 3; ++a)
        for (int bq = 0; bq < 3; ++bq)
            for (int cq = 0; cq < 3; ++cq) {
                float wt = w[0][a] * w[1][bq] * w[2][cq];
                size_t g = ((size_t)W[0][a] * n + W[1][bq]) * n + W[2][cq];
                #pragma unroll
                for (int ch = 0; ch < 8; ++ch)
                    atomicAdd(out + (size_t)ch * n3 + g, wt * e[ch]);
            }
}

// ---------------- fallback: interleaved atomics + transpose ----------------

__global__ __launch_bounds__(256) void deposit_tsc8_ilv(
    const float* __restrict__ pos,
    const float* __restrict__ cell,
    const float* __restrict__ emb,
    float* __restrict__ ws,
    int total, int n)
{
    int t = blockIdx.x * blockDim.x + threadIdx.x;
    if (t >= total) return;
    int atom = t / 27;
    int c    = t - atom * 27;
    int a    = c / 9;
    int rem  = c - a * 9;
    int b    = rem / 3;
    int cc   = rem - b * 3;

    float inv_sp = inv_spacing(cell, n);

    float px = pos[3 * atom + 0] * inv_sp;
    float py = pos[3 * atom + 1] * inv_sp;
    float pz = pos[3 * atom + 2] * inv_sp;

    int cx = (int)rintf(px);  float dx = px - (float)cx;
    int cy = (int)rintf(py);  float dy = py - (float)cy;
    int cz = (int)rintf(pz);  float dz = pz - (float)cz;

    float w = tsc_w(a - 1, dx) * tsc_w(b - 1, dy) * tsc_w(cc - 1, dz);

    int x = cx - 1 + a;  if (x < 0) x += n; else if (x >= n) x -= n;
    int y = cy - 1 + b;  if (y < 0) y += n; else if (y >= n) y -= n;
    int z = cz - 1 + cc; if (z < 0) z += n; else if (z >= n) z -= n;

    const float4* e4 = (const float4*)(emb + (size_t)atom * 8);
    float4 e0 = e4[0], e1 = e4[1];

    float* p = ws + ((size_t)((x * n + y) * n + z)) * 8;
    atomicAdd(p + 0, w * e0.x);
    atomicAdd(p + 1, w * e0.y);
    atomicAdd(p + 2, w * e0.z);
    atomicAdd(p + 3, w * e0.w);
    atomicAdd(p + 4, w * e1.x);
    atomicAdd(p + 5, w * e1.y);
    atomicAdd(p + 6, w * e1.z);
    atomicAdd(p + 7, w * e1.w);
}

__global__ __launch_bounds__(256) void transpose_ilv8(
    const float* __restrict__ ws, float* __restrict__ out, int n3)
{
    int t = blockIdx.x * blockDim.x + threadIdx.x;
    int g0 = t * 4;
    if (g0 >= n3) return;
    const float4* w4 = (const float4*)(ws + (size_t)g0 * 8);
    float4 r0 = w4[0], r1 = w4[1];
    float4 r2 = w4[2], r3 = w4[3];
    float4 r4 = w4[4], r5 = w4[5];
    float4 r6 = w4[6], r7 = w4[7];

    *(float4*)(out + (size_t)0 * n3 + g0) = make_float4(r0.x, r2.x, r4.x, r6.x);
    *(float4*)(out + (size_t)1 * n3 + g0) = make_float4(r0.y, r2.y, r4.y, r6.y);
    *(float4*)(out + (size_t)2 * n3 + g0) = make_float4(r0.z, r2.z, r4.z, r6.z);
    *(float4*)(out + (size_t)3 * n3 + g0) = make_float4(r0.w, r2.w, r4.w, r6.w);
    *(float4*)(out + (size_t)4 * n3 + g0) = make_float4(r1.x, r3.x, r5.x, r7.x);
    *(float4*)(out + (size_t)5 * n3 + g0) = make_float4(r1.y, r3.y, r5.y, r7.y);
    *(float4*)(out + (size_t)6 * n3 + g0) = make_float4(r1.z, r3.z, r5.z, r7.z);
    *(float4*)(out + (size_t)7 * n3 + g0) = make_float4(r1.w, r3.w, r5.w, r7.w);
}

// ---------------- fallback: generic planar atomics ----------------

__global__ __launch_bounds__(256) void deposit_tsc_gen(
    const float* __restrict__ pos,
    const float* __restrict__ cell,
    const float* __restrict__ emb,
    float* __restrict__ out,
    int N, int n, int C)
{
    int i = blockIdx.x * blockDim.x + threadIdx.x;
    if (i >= N) return;

    float inv_sp = inv_spacing(cell, n);

    float p[3], d[3];
    int c0[3];
    #pragma unroll
    for (int k = 0; k < 3; ++k) {
        p[k] = pos[3 * i + k] * inv_sp;
        c0[k] = (int)rintf(p[k]);
        d[k] = p[k] - (float)c0[k];
    }
    float w[3][3];
    #pragma unroll
    for (int k = 0; k < 3; ++k) {
        float dd = d[k], d2 = dd * dd;
        w[k][0] = 0.125f * (1.0f - 4.0f * dd + 4.0f * d2);
        w[k][1] = 0.25f  * (3.0f - 4.0f * d2);
        w[k][2] = 0.125f * (1.0f + 4.0f * dd + 4.0f * d2);
    }
    int W[3][3];
    #pragma unroll
    for (int k = 0; k < 3; ++k) {
        #pragma unroll
        for (int a = 0; a < 3; ++a) {
            int v = c0[k] - 1 + a; if (v < 0) v += n; else if (v >= n) v -= n;
            W[k][a] = v;
        }
    }
    int n3 = n * n * n;
    for (int a = 0; a < 3; ++a)
        for (int b = 0; b < 3; ++b)
            for (int cc = 0; cc < 3; ++cc) {
                float wt = w[0][a] * w[1][b] * w[2][cc];
                int g = (W[0][a] * n + W[1][b]) * n + W[2][cc];
                for (int ch = 0; ch < C; ++ch)
                    atomicAdd(out + (size_t)ch * n3 + g, wt * emb[(size_t)i * C + ch]);
            }
}

extern "C" void kernel_launch(void* const* d_in, const int* in_sizes, int n_in,
                              void* d_out, int out_size, void* d_ws, size_t ws_size,
                              hipStream_t stream) {
    const float* pos  = (const float*)d_in[0];
    const float* cell = (const float*)d_in[1];
    const float* emb  = (const float*)d_in[2];
    float* out = (float*)d_out;
    float* ws  = (float*)d_ws;

    int N = in_sizes[0] / 3;
    int C = in_sizes[2] / N;
    long long n3l = (long long)out_size / C;
    int n = (int)llroundf(cbrtf((float)n3l));
    int n3 = (int)n3l;

    int block = 256;

    // ---- small-tile slab fast path ----
    {
        int nb = n * n;
        size_t lds_bytes = (size_t)8 * TYS * n * sizeof(float);   // 64n B
        size_t rec_off = (((size_t)nb + 4 + (size_t)N) * sizeof(int) + 15) & ~(size_t)15;
        size_t need = rec_off + (size_t)nb * KColCAP * 48;
        bool slab_ok = (C == 8) && (n % TYS == 0) && n >= 8 && n <= 512
                       && lds_bytes <= 64 * 1024
                       && ws_size >= need
                       && ((long long)n * n * n == n3l);
        if (slab_ok) {
            int* counts  = (int*)d_ws;
            int* ovf_cnt = counts + nb;
            int* ovf     = counts + nb + 4;
            float4* binrec = (float4*)((char*)d_ws + rec_off);

            (void)hipMemsetAsync(counts, 0, (size_t)(nb + 4) * sizeof(int), stream);
            fill_recs<<<(N + block - 1) / block, block, 0, stream>>>(
                pos, cell, emb, counts, ovf_cnt, binrec, ovf, N, n);
            int nyg = n / TYS;
            deposit_slab2<<<n * nyg, BLK, lds_bytes, stream>>>(
                binrec, counts, out, n, nyg);
            deposit_overflow<<<(N + block - 1) / block, block, 0, stream>>>(
                pos, cell, emb, ovf_cnt, ovf, out, n);
            return;
        }
    }

    // ---- fallback: interleaved atomics + transpose ----
    size_t need = (size_t)out_size * sizeof(float);
    if (C == 8 && ws_size >= need && (n3 % 4) == 0) {
        (void)hipMemsetAsync(d_ws, 0, need, stream);
        int total = N * 27;
        deposit_tsc8_ilv<<<(total + block - 1) / block, block, 0, stream>>>(
            pos, cell, emb, ws, total, n);
        int tthreads = n3 / 4;
        transpose_ilv8<<<(tthreads + block - 1) / block, block, 0, stream>>>(
            ws, out, n3);
    } else {
        (void)hipMemsetAsync(d_out, 0, (size_t)out_size * sizeof(float), stream);
        int grid = (N + block - 1) / block;
        deposit_tsc_gen<<<grid, block, 0, stream>>>(pos, cell, emb, out, N, n, C);
    }
}